// Round 5
// baseline (236.777 us; speedup 1.0000x reference)
//
#include <hip/hip_runtime.h>

// PoseLoss round 5: single fused kernel, 1-wave blocks.
// - Each block = 1 wave owns 256 samples; q streams load direct float4
//   (per-sample aligned); xyz/gt load as lane*16B wave-segments into a
//   wave-private 16 KiB LDS region (no __syncthreads; same-wave lgkmcnt only).
// - sched_barrier(0) after load issue pins all 25 dwordx4 in flight (R1's
//   failure was the compiler collapsing staging to VGPR=32 / ~3-deep MLP).
// - Final reduction folded in via last-block-done: partial[blk] ->
//   threadfence -> atomicAdd(counter); block seeing old==N-1 reduces all
//   partials and writes out. Counter zeroed per launch by hipMemsetAsync
//   (graph-capture legal). Deterministic: fixed array, fixed reduce order.

#define W1_XYZ 0.3f
#define W2_XYZ 0.3f
#define W3_XYZ 1.0f
#define W1_WPQR 150.0f
#define W2_WPQR 150.0f
#define W3_WPQR 500.0f

constexpr int B_TOTAL = 1048576;
constexpr int BLOCK   = 64;            // one wave per block
constexpr int SPW     = 256;           // samples per wave
constexpr int NBLOCKS = B_TOTAL / SPW; // 4096

__global__ __launch_bounds__(BLOCK) void pose_loss_fused(
    const float* __restrict__ p1x, const float* __restrict__ p1q,
    const float* __restrict__ p2x, const float* __restrict__ p2q,
    const float* __restrict__ p3x, const float* __restrict__ p3q,
    const float* __restrict__ gt,
    float* __restrict__ partial, unsigned* __restrict__ counter,
    float* __restrict__ out)
{
    __shared__ __align__(16) float lds[4096];   // 16 KiB: x1,x2,x3 (768 f each) + gt (1792 f)
    const int  lane = threadIdx.x;
    const long W    = blockIdx.x;

    float* Lx1 = lds;
    float* Lx2 = lds + 768;
    float* Lx3 = lds + 1536;
    float* Lg  = lds + 2304;

    // ---- direct per-sample q loads (16 B aligned, 1 KiB contiguous per instr) ----
    const float4* q1p = (const float4*)p1q;
    const float4* q2p = (const float4*)p2q;
    const float4* q3p = (const float4*)p3q;
    float4 q1v[4], q2v[4], q3v[4];
    #pragma unroll
    for (int k = 0; k < 4; ++k) {
        const long s = W * SPW + (long)(k * 64 + lane);
        q1v[k] = q1p[s];
        q2v[k] = q2p[s];
        q3v[k] = q3p[s];
    }

    // ---- wave-segment loads (lane*16 B) for xyz (3 KiB/stream) + gt (7 KiB) ----
    const float4* x1p = (const float4*)p1x;
    const float4* x2p = (const float4*)p2x;
    const float4* x3p = (const float4*)p3x;
    const float4* gp  = (const float4*)gt;
    float4 xs1[3], xs2[3], xs3[3], gs[7];
    #pragma unroll
    for (int j = 0; j < 3; ++j) xs1[j] = x1p[W * 192 + (long)(j * 64 + lane)];
    #pragma unroll
    for (int j = 0; j < 3; ++j) xs2[j] = x2p[W * 192 + (long)(j * 64 + lane)];
    #pragma unroll
    for (int j = 0; j < 3; ++j) xs3[j] = x3p[W * 192 + (long)(j * 64 + lane)];
    #pragma unroll
    for (int j = 0; j < 7; ++j) gs[j]  = gp [W * 448 + (long)(j * 64 + lane)];

    // pin: all 25 global loads issued before any LDS traffic / compute
    __builtin_amdgcn_sched_barrier(0);

    // redistribute through wave-private LDS (ds_write_b128 stride-16 B:
    // conflict-free; no cross-wave sharing -> no barrier)
    #pragma unroll
    for (int j = 0; j < 3; ++j) ((float4*)Lx1)[j * 64 + lane] = xs1[j];
    #pragma unroll
    for (int j = 0; j < 3; ++j) ((float4*)Lx2)[j * 64 + lane] = xs2[j];
    #pragma unroll
    for (int j = 0; j < 3; ++j) ((float4*)Lx3)[j * 64 + lane] = xs3[j];
    #pragma unroll
    for (int j = 0; j < 7; ++j) ((float4*)Lg )[j * 64 + lane] = gs[j];

    // ---- compute 4 samples per thread (s = 64k + lane) ----
    // LDS read strides 3 and 7 floats: coprime to 32 banks -> conflict-free.
    float acc = 0.0f;
    #pragma unroll
    for (int k = 0; k < 4; ++k) {
        const int s = k * 64 + lane;
        const float px  = Lg[7*s + 0];
        const float py  = Lg[7*s + 1];
        const float pz  = Lg[7*s + 2];
        const float qa0 = Lg[7*s + 3];
        const float qb0 = Lg[7*s + 4];
        const float qc0 = Lg[7*s + 5];
        const float qd0 = Lg[7*s + 6];
        // 1/max(sqrt(d), 1e-12) == min(rsq(d), 1e12) for d >= 0
        const float d   = qa0*qa0 + qb0*qb0 + qc0*qc0 + qd0*qd0;
        const float inv = fminf(__builtin_amdgcn_rsqf(d), 1e12f);
        const float qa = qa0 * inv, qb = qb0 * inv, qc = qc0 * inv, qd = qd0 * inv;

        float dx, dy, dz, dw;

        dx = Lx1[3*s + 0] - px; dy = Lx1[3*s + 1] - py; dz = Lx1[3*s + 2] - pz;
        const float l1x = __builtin_amdgcn_sqrtf(dx*dx + dy*dy + dz*dz);
        dw = q1v[k].x - qa; dx = q1v[k].y - qb; dy = q1v[k].z - qc; dz = q1v[k].w - qd;
        const float l1q = __builtin_amdgcn_sqrtf(dw*dw + dx*dx + dy*dy + dz*dz);

        dx = Lx2[3*s + 0] - px; dy = Lx2[3*s + 1] - py; dz = Lx2[3*s + 2] - pz;
        const float l2x = __builtin_amdgcn_sqrtf(dx*dx + dy*dy + dz*dz);
        dw = q2v[k].x - qa; dx = q2v[k].y - qb; dy = q2v[k].z - qc; dz = q2v[k].w - qd;
        const float l2q = __builtin_amdgcn_sqrtf(dw*dw + dx*dx + dy*dy + dz*dz);

        dx = Lx3[3*s + 0] - px; dy = Lx3[3*s + 1] - py; dz = Lx3[3*s + 2] - pz;
        const float l3x = __builtin_amdgcn_sqrtf(dx*dx + dy*dy + dz*dz);
        dw = q3v[k].x - qa; dx = q3v[k].y - qb; dy = q3v[k].z - qc; dz = q3v[k].w - qd;
        const float l3q = __builtin_amdgcn_sqrtf(dw*dw + dx*dx + dy*dy + dz*dz);

        acc += W1_XYZ * (l1x + W1_WPQR * l1q)
             + W2_XYZ * (l2x + W2_WPQR * l2q)
             + W3_XYZ * (l3x + W3_WPQR * l3q);
    }

    // wave-64 reduction -> one partial per block
    #pragma unroll
    for (int off = 32; off > 0; off >>= 1)
        acc += __shfl_down(acc, off);
    if (lane == 0) partial[W] = acc;

    // ---- last-block-done final reduction ----
    __threadfence();                      // release: partial store visible device-wide
    unsigned old = 0;
    if (lane == 0) old = atomicAdd(counter, 1u);
    old = __shfl(old, 0);
    if (old == (unsigned)(NBLOCKS - 1)) {
        __threadfence();                  // acquire: see all partials
        float s2 = 0.0f;
        #pragma unroll
        for (int j = 0; j < NBLOCKS / 4 / 64; ++j) {   // 16 float4 per lane
            const float4 v = ((const float4*)partial)[j * 64 + lane];
            s2 += (v.x + v.y) + (v.z + v.w);
        }
        #pragma unroll
        for (int off = 32; off > 0; off >>= 1)
            s2 += __shfl_down(s2, off);
        if (lane == 0) out[0] = s2 * (1.0f / (float)B_TOTAL);
    }
}

extern "C" void kernel_launch(void* const* d_in, const int* in_sizes, int n_in,
                              void* d_out, int out_size, void* d_ws, size_t ws_size,
                              hipStream_t stream) {
    const float* p1x = (const float*)d_in[0];
    const float* p1q = (const float*)d_in[1];
    const float* p2x = (const float*)d_in[2];
    const float* p2q = (const float*)d_in[3];
    const float* p3x = (const float*)d_in[4];
    const float* p3q = (const float*)d_in[5];
    const float* gt  = (const float*)d_in[6];
    float* out = (float*)d_out;

    float*    partial = (float*)d_ws;                       // 4096 floats = 16 KiB
    unsigned* counter = (unsigned*)((char*)d_ws + 16384);   // 4 bytes

    hipMemsetAsync((void*)counter, 0, sizeof(unsigned), stream);  // async, graph-legal
    pose_loss_fused<<<NBLOCKS, BLOCK, 0, stream>>>(
        p1x, p1q, p2x, p2q, p3x, p3q, gt, partial, counter, out);
}

// Round 6
// 24.804 us; speedup vs baseline: 9.5459x; 9.5459x over previous
//
#include <hip/hip_runtime.h>

// PoseLoss round 6: two-kernel structure (R4, proven 24.5us) with
//  (a) 1-wave blocks: BLOCK=64, 16 KiB LDS -> 10 independent resident
//      waves/CU, no coupled block-exit bubbles (R4 had 2x4-wave blocks/CU);
//  (b) LDS-bound loads (xyz, gt) issued BEFORE q loads, so the ds_writes
//      drain progressively under the in-flight q loads (vmcnt is
//      issue-ordered; R4's q-first order stalled every ds_write behind
//      all 25 loads).
// R5 post-mortem: fused last-block-done finalize = 4096 device-scope
// fences + same-address atomics across non-coherent XCD L2s -> 227us.
// Never again; the 2nd launch (~2-3us) is cheaper.

#define W1_XYZ 0.3f
#define W2_XYZ 0.3f
#define W3_XYZ 1.0f
#define W1_WPQR 150.0f
#define W2_WPQR 150.0f
#define W3_WPQR 500.0f

constexpr int B_TOTAL = 1048576;
constexpr int BLOCK   = 64;            // one wave per block
constexpr int SPW     = 256;           // samples per wave
constexpr int NBLOCKS = B_TOTAL / SPW; // 4096

__global__ __launch_bounds__(BLOCK) void pose_loss_partial(
    const float* __restrict__ p1x, const float* __restrict__ p1q,
    const float* __restrict__ p2x, const float* __restrict__ p2q,
    const float* __restrict__ p3x, const float* __restrict__ p3q,
    const float* __restrict__ gt, float* __restrict__ partial)
{
    __shared__ __align__(16) float lds[4096];  // 16 KiB: x1,x2,x3 (768 f) + gt (1792 f)
    const int  lane = threadIdx.x;
    const long W    = blockIdx.x;

    float* Lx1 = lds;
    float* Lx2 = lds + 768;
    float* Lx3 = lds + 1536;
    float* Lg  = lds + 2304;

    // ---- LDS-bound wave-segment loads FIRST (lane*16 B, perfectly coalesced)
    const float4* x1p = (const float4*)p1x;
    const float4* x2p = (const float4*)p2x;
    const float4* x3p = (const float4*)p3x;
    const float4* gp  = (const float4*)gt;
    float4 xs1[3], xs2[3], xs3[3], gs[7];
    #pragma unroll
    for (int j = 0; j < 3; ++j) xs1[j] = x1p[W * 192 + (long)(j * 64 + lane)];
    #pragma unroll
    for (int j = 0; j < 3; ++j) xs2[j] = x2p[W * 192 + (long)(j * 64 + lane)];
    #pragma unroll
    for (int j = 0; j < 3; ++j) xs3[j] = x3p[W * 192 + (long)(j * 64 + lane)];
    #pragma unroll
    for (int j = 0; j < 7; ++j) gs[j]  = gp [W * 448 + (long)(j * 64 + lane)];

    // ---- q loads second: consumed only at the end of compute ----
    const float4* q1p = (const float4*)p1q;
    const float4* q2p = (const float4*)p2q;
    const float4* q3p = (const float4*)p3q;
    float4 q1v[4], q2v[4], q3v[4];
    #pragma unroll
    for (int k = 0; k < 4; ++k) {
        const long s = W * SPW + (long)(k * 64 + lane);
        q1v[k] = q1p[s];
        q2v[k] = q2p[s];
        q3v[k] = q3p[s];
    }

    // redistribute through wave-private LDS (ds_write_b128 stride-16 B:
    // conflict-free; single wave -> no barrier, lgkmcnt ordering only)
    #pragma unroll
    for (int j = 0; j < 3; ++j) ((float4*)Lx1)[j * 64 + lane] = xs1[j];
    #pragma unroll
    for (int j = 0; j < 3; ++j) ((float4*)Lx2)[j * 64 + lane] = xs2[j];
    #pragma unroll
    for (int j = 0; j < 3; ++j) ((float4*)Lx3)[j * 64 + lane] = xs3[j];
    #pragma unroll
    for (int j = 0; j < 7; ++j) ((float4*)Lg )[j * 64 + lane] = gs[j];

    // ---- compute 4 samples per thread (s = 64k + lane) ----
    // LDS read strides 3 and 7 floats: coprime to 32 banks -> conflict-free.
    float acc = 0.0f;
    #pragma unroll
    for (int k = 0; k < 4; ++k) {
        const int s = k * 64 + lane;
        const float px  = Lg[7*s + 0];
        const float py  = Lg[7*s + 1];
        const float pz  = Lg[7*s + 2];
        const float qa0 = Lg[7*s + 3];
        const float qb0 = Lg[7*s + 4];
        const float qc0 = Lg[7*s + 5];
        const float qd0 = Lg[7*s + 6];
        // 1/max(sqrt(d), 1e-12) == min(rsq(d), 1e12) for d >= 0
        const float d   = qa0*qa0 + qb0*qb0 + qc0*qc0 + qd0*qd0;
        const float inv = fminf(__builtin_amdgcn_rsqf(d), 1e12f);
        const float qa = qa0 * inv, qb = qb0 * inv, qc = qc0 * inv, qd = qd0 * inv;

        float dx, dy, dz, dw;

        dx = Lx1[3*s + 0] - px; dy = Lx1[3*s + 1] - py; dz = Lx1[3*s + 2] - pz;
        const float l1x = __builtin_amdgcn_sqrtf(dx*dx + dy*dy + dz*dz);
        dw = q1v[k].x - qa; dx = q1v[k].y - qb; dy = q1v[k].z - qc; dz = q1v[k].w - qd;
        const float l1q = __builtin_amdgcn_sqrtf(dw*dw + dx*dx + dy*dy + dz*dz);

        dx = Lx2[3*s + 0] - px; dy = Lx2[3*s + 1] - py; dz = Lx2[3*s + 2] - pz;
        const float l2x = __builtin_amdgcn_sqrtf(dx*dx + dy*dy + dz*dz);
        dw = q2v[k].x - qa; dx = q2v[k].y - qb; dy = q2v[k].z - qc; dz = q2v[k].w - qd;
        const float l2q = __builtin_amdgcn_sqrtf(dw*dw + dx*dx + dy*dy + dz*dz);

        dx = Lx3[3*s + 0] - px; dy = Lx3[3*s + 1] - py; dz = Lx3[3*s + 2] - pz;
        const float l3x = __builtin_amdgcn_sqrtf(dx*dx + dy*dy + dz*dz);
        dw = q3v[k].x - qa; dx = q3v[k].y - qb; dy = q3v[k].z - qc; dz = q3v[k].w - qd;
        const float l3q = __builtin_amdgcn_sqrtf(dw*dw + dx*dx + dy*dy + dz*dz);

        acc += W1_XYZ * (l1x + W1_WPQR * l1q)
             + W2_XYZ * (l2x + W2_WPQR * l2q)
             + W3_XYZ * (l3x + W3_WPQR * l3q);
    }

    // wave-64 reduction -> one partial per block (no barrier anywhere)
    #pragma unroll
    for (int off = 32; off > 0; off >>= 1)
        acc += __shfl_down(acc, off);
    if (lane == 0) partial[W] = acc;
}

__global__ __launch_bounds__(1024) void pose_loss_final(
    const float* __restrict__ partial, float* __restrict__ out, float scale)
{
    const int tid = threadIdx.x;
    const float4 v = ((const float4*)partial)[tid];   // 1024 x float4 = 4096 partials
    float acc = (v.x + v.y) + (v.z + v.w);

    #pragma unroll
    for (int off = 32; off > 0; off >>= 1)
        acc += __shfl_down(acc, off);

    __shared__ float smem[16];
    if ((tid & 63) == 0) smem[tid >> 6] = acc;
    __syncthreads();
    if (tid == 0) {
        float s = 0.0f;
        #pragma unroll
        for (int w = 0; w < 16; ++w) s += smem[w];
        out[0] = s * scale;
    }
}

extern "C" void kernel_launch(void* const* d_in, const int* in_sizes, int n_in,
                              void* d_out, int out_size, void* d_ws, size_t ws_size,
                              hipStream_t stream) {
    const float* p1x = (const float*)d_in[0];
    const float* p1q = (const float*)d_in[1];
    const float* p2x = (const float*)d_in[2];
    const float* p2q = (const float*)d_in[3];
    const float* p3x = (const float*)d_in[4];
    const float* p3q = (const float*)d_in[5];
    const float* gt  = (const float*)d_in[6];
    float* out = (float*)d_out;
    float* partial = (float*)d_ws;   // 4096 floats = 16 KiB

    pose_loss_partial<<<NBLOCKS, BLOCK, 0, stream>>>(p1x, p1q, p2x, p2q, p3x, p3q, gt, partial);
    pose_loss_final<<<1, 1024, 0, stream>>>(partial, out, 1.0f / (float)B_TOTAL);
}